// Round 2
// baseline (587.333 us; speedup 1.0000x reference)
//
#include <hip/hip_runtime.h>

// Linear_AB_I8_DE_F32: y[m,n] = 0.01 * sum_k x8[m,k]*w8[n,k] + bias[n]
// M=4096, N=11008, K=4096. int8 values in int32 containers.
//
// R2: (a) LDS XOR-chunk swizzle to kill 4-way bank conflicts on frag reads
//     (stage global chunk c^(row&3) into linear slot c; read slot q^(row&3)),
//     (b) pack kernel v2: 16 int32 -> int4 store per thread.

#define M_DIM 4096
#define N_DIM 11008
#define K_DIM 4096
#define BM 128
#define BN 128
#define BK 64
#define ALPHA 0.01f

typedef __attribute__((ext_vector_type(4))) int i32x4;

static __device__ __forceinline__ int pack4(int4 v) {
    return (v.x & 0xff) | ((v.y & 0xff) << 8) |
           ((v.z & 0xff) << 16) | ((unsigned)(v.w & 0xff) << 24);
}

// ---------------- pack: 16 int32 -> 16 int8 per thread ----------------
__global__ __launch_bounds__(256) void pack_i8_kernel(
    const int4* __restrict__ in, int4* __restrict__ out, int n16)
{
    int i = blockIdx.x * blockDim.x + threadIdx.x;
    if (i < n16) {
        const int4* p = in + (size_t)4 * i;
        int4 a = p[0], b = p[1], c = p[2], d = p[3];
        int4 r;
        r.x = pack4(a); r.y = pack4(b); r.z = pack4(c); r.w = pack4(d);
        out[i] = r;
    }
}

// ---------------- GEMM ----------------
__global__ __launch_bounds__(256) void gemm_i8_kernel(
    const char* __restrict__ A,     // [M][K] int8 row-major
    const char* __restrict__ B,     // [N][K] int8 row-major
    const float* __restrict__ bias, // [N]
    float* __restrict__ C)          // [M][N] fp32
{
    __shared__ __attribute__((aligned(16))) char As[BM * BK]; // 8 KB
    __shared__ __attribute__((aligned(16))) char Bs[BN * BK]; // 8 KB

    const int tid  = threadIdx.x;
    const int lane = tid & 63;
    const int wave = tid >> 6;
    const int waveM = (wave >> 1) * 64;
    const int waveN = (wave & 1) * 64;
    const int bm = blockIdx.y * BM;
    const int bn = blockIdx.x * BN;

    const int lrow  = lane & 15;
    const int lquad = lane >> 4;

    // staging: 4 threads per 64B row; XOR-swizzle which global chunk this
    // lane fetches so LDS slot c holds global chunk c^(row&3).
    const int srow = tid >> 2;
    const int scol = ((tid & 3) ^ (srow & 3)) * 16;
    const char* Abase = A + (size_t)(bm + srow) * K_DIM + scol;
    const char* Bbase = B + (size_t)(bn + srow) * K_DIM + scol;

    // frag-read swizzled chunk offset: global chunk lquad lives at slot
    // lquad ^ (row&3); row&3 == lrow&3 (waveM, i*16 are multiples of 4).
    const int swq = (lquad ^ (lrow & 3)) * 16;

    i32x4 acc[4][4] = {};

    for (int k0 = 0; k0 < K_DIM; k0 += BK) {
        __builtin_amdgcn_global_load_lds(
            (const __attribute__((address_space(1))) void*)(Abase + k0),
            (__attribute__((address_space(3))) void*)(As + tid * 16), 16, 0, 0);
        __builtin_amdgcn_global_load_lds(
            (const __attribute__((address_space(1))) void*)(Abase + (size_t)64 * K_DIM + k0),
            (__attribute__((address_space(3))) void*)(As + 4096 + tid * 16), 16, 0, 0);
        __builtin_amdgcn_global_load_lds(
            (const __attribute__((address_space(1))) void*)(Bbase + k0),
            (__attribute__((address_space(3))) void*)(Bs + tid * 16), 16, 0, 0);
        __builtin_amdgcn_global_load_lds(
            (const __attribute__((address_space(1))) void*)(Bbase + (size_t)64 * K_DIM + k0),
            (__attribute__((address_space(3))) void*)(Bs + 4096 + tid * 16), 16, 0, 0);
        __syncthreads();

        i32x4 a[4], b[4];
#pragma unroll
        for (int i = 0; i < 4; i++)
            a[i] = *(const i32x4*)(As + (waveM + i * 16 + lrow) * BK + swq);
#pragma unroll
        for (int j = 0; j < 4; j++)
            b[j] = *(const i32x4*)(Bs + (waveN + j * 16 + lrow) * BK + swq);

#pragma unroll
        for (int i = 0; i < 4; i++)
#pragma unroll
            for (int j = 0; j < 4; j++)
                acc[i][j] = __builtin_amdgcn_mfma_i32_16x16x64_i8(a[i], b[j], acc[i][j], 0, 0, 0);

        __syncthreads();
    }

    // epilogue: C/D layout col=lane&15, row=(lane>>4)*4+reg
#pragma unroll
    for (int i = 0; i < 4; i++) {
        const int r0 = bm + waveM + i * 16 + lquad * 4;
#pragma unroll
        for (int j = 0; j < 4; j++) {
            const int c0 = bn + waveN + j * 16 + lrow;
            const float bv = bias[c0];
#pragma unroll
            for (int r = 0; r < 4; r++) {
                C[(size_t)(r0 + r) * N_DIM + c0] = ALPHA * (float)acc[i][j][r] + bv;
            }
        }
    }
}

extern "C" void kernel_launch(void* const* d_in, const int* in_sizes, int n_in,
                              void* d_out, int out_size, void* d_ws, size_t ws_size,
                              hipStream_t stream) {
    const int*   x    = (const int*)d_in[0];
    const int*   w    = (const int*)d_in[1];
    const float* bias = (const float*)d_in[2];
    float*       out  = (float*)d_out;

    char* Ap = (char*)d_ws;
    char* Wp = (char*)d_ws + (size_t)M_DIM * K_DIM;

    const int n16x = M_DIM * K_DIM / 16;   // 1,048,576 -> 4096 blocks
    const int n16w = N_DIM * K_DIM / 16;   // 2,818,048 -> 11008 blocks
    pack_i8_kernel<<<n16x / 256, 256, 0, stream>>>((const int4*)x, (int4*)Ap, n16x);
    pack_i8_kernel<<<n16w / 256, 256, 0, stream>>>((const int4*)w, (int4*)Wp, n16w);

    dim3 grid(N_DIM / BN, M_DIM / BM);  // (86, 32)
    gemm_i8_kernel<<<grid, 256, 0, stream>>>(Ap, Wp, bias, out);
}

// Round 3
// 555.522 us; speedup vs baseline: 1.0573x; 1.0573x over previous
//
#include <hip/hip_runtime.h>

// Linear_AB_I8_DE_F32: y[m,n] = 0.01 * sum_k x8[m,k]*w8[n,k] + bias[n]
// M=4096, N=11008, K=4096. int8 values in int32 containers.
//
// R3: (a) correct LDS XOR swizzle key ((row>>1)&3) -> conflict-free batches
//     for ds_read_b128 frag reads (R2's (row&3) key provably changed nothing);
//     (b) 256x128 block, 128x64 per wave (8x4 frags) -> reads/MFMA 0.5->0.375.

#define M_DIM 4096
#define N_DIM 11008
#define K_DIM 4096
#define BM 256
#define BN 128
#define BK 64
#define ALPHA 0.01f

typedef __attribute__((ext_vector_type(4))) int i32x4;

static __device__ __forceinline__ int pack4(int4 v) {
    return (v.x & 0xff) | ((v.y & 0xff) << 8) |
           ((v.z & 0xff) << 16) | ((unsigned)(v.w & 0xff) << 24);
}

// ---------------- fused pack: 16 int32 -> 16 int8 per thread ----------------
__global__ __launch_bounds__(256) void pack_i8_kernel(
    const int4* __restrict__ x, int4* __restrict__ xout, int n16x,
    const int4* __restrict__ w, int4* __restrict__ wout, int n16_total)
{
    int i = blockIdx.x * blockDim.x + threadIdx.x;
    if (i >= n16_total) return;
    const int4* src;
    int4* dst;
    int idx;
    if (i < n16x) { src = x; dst = xout; idx = i; }
    else          { src = w; dst = wout; idx = i - n16x; }
    const int4* p = src + (size_t)4 * idx;
    int4 a = p[0], b = p[1], c = p[2], d = p[3];
    int4 r;
    r.x = pack4(a); r.y = pack4(b); r.z = pack4(c); r.w = pack4(d);
    dst[idx] = r;
}

// ---------------- GEMM ----------------
__global__ __launch_bounds__(256, 2) void gemm_i8_kernel(
    const char* __restrict__ A,     // [M][K] int8 row-major
    const char* __restrict__ B,     // [N][K] int8 row-major
    const float* __restrict__ bias, // [N]
    float* __restrict__ C)          // [M][N] fp32
{
    __shared__ __attribute__((aligned(16))) char As[BM * BK]; // 16 KB
    __shared__ __attribute__((aligned(16))) char Bs[BN * BK]; //  8 KB

    const int tid  = threadIdx.x;
    const int lane = tid & 63;
    const int wave = tid >> 6;
    const int waveM = (wave >> 1) * 128;   // 2x2 wave grid: 128x64 per wave
    const int waveN = (wave & 1) * 64;
    const int bm = blockIdx.y * BM;
    const int bn = blockIdx.x * BN;

    const int lrow  = lane & 15;
    const int lquad = lane >> 4;

    // staging: thread tid covers 16B unit s=tid of a 64-row chunk.
    // LDS slot s holds global (row = s>>2, chunk = (s&3) ^ ((s>>3)&3)).
    // key (row>>1)&3 has row-parity-independent bits -> per-8-lane batches of
    // frag reads hit all 8 bank groups (conflict-free).
    const int srow = tid >> 2;
    const int scol = ((tid & 3) ^ ((tid >> 3) & 3)) * 16;
    const char* Abase = A + (size_t)(bm + srow) * K_DIM + scol;
    const char* Bbase = B + (size_t)(bn + srow) * K_DIM + scol;

    // frag read: global chunk lquad of row r lives at slot lquad ^ ((r>>1)&3);
    // (r>>1)&3 == (lrow>>1)&3 for any 16-aligned tile base.
    const int swq = (lquad ^ ((lrow >> 1) & 3)) * 16;

    i32x4 acc[8][4] = {};

    for (int k0 = 0; k0 < K_DIM; k0 += BK) {
        // A: 4 chunks of 64 rows; B: 2 chunks
#pragma unroll
        for (int c = 0; c < 4; c++)
            __builtin_amdgcn_global_load_lds(
                (const __attribute__((address_space(1))) void*)(Abase + (size_t)(64 * c) * K_DIM + k0),
                (__attribute__((address_space(3))) void*)(As + c * 4096 + tid * 16), 16, 0, 0);
#pragma unroll
        for (int c = 0; c < 2; c++)
            __builtin_amdgcn_global_load_lds(
                (const __attribute__((address_space(1))) void*)(Bbase + (size_t)(64 * c) * K_DIM + k0),
                (__attribute__((address_space(3))) void*)(Bs + c * 4096 + tid * 16), 16, 0, 0);
        __syncthreads();

        i32x4 a[8], b[4];
#pragma unroll
        for (int i = 0; i < 8; i++)
            a[i] = *(const i32x4*)(As + (waveM + i * 16 + lrow) * BK + swq);
#pragma unroll
        for (int j = 0; j < 4; j++)
            b[j] = *(const i32x4*)(Bs + (waveN + j * 16 + lrow) * BK + swq);

#pragma unroll
        for (int i = 0; i < 8; i++)
#pragma unroll
            for (int j = 0; j < 4; j++)
                acc[i][j] = __builtin_amdgcn_mfma_i32_16x16x64_i8(a[i], b[j], acc[i][j], 0, 0, 0);

        __syncthreads();
    }

    // epilogue: C/D layout col=lane&15, row=(lane>>4)*4+reg
#pragma unroll
    for (int i = 0; i < 8; i++) {
        const int r0 = bm + waveM + i * 16 + lquad * 4;
#pragma unroll
        for (int j = 0; j < 4; j++) {
            const int c0 = bn + waveN + j * 16 + lrow;
            const float bv = bias[c0];
#pragma unroll
            for (int r = 0; r < 4; r++) {
                C[(size_t)(r0 + r) * N_DIM + c0] = ALPHA * (float)acc[i][j][r] + bv;
            }
        }
    }
}

extern "C" void kernel_launch(void* const* d_in, const int* in_sizes, int n_in,
                              void* d_out, int out_size, void* d_ws, size_t ws_size,
                              hipStream_t stream) {
    const int*   x    = (const int*)d_in[0];
    const int*   w    = (const int*)d_in[1];
    const float* bias = (const float*)d_in[2];
    float*       out  = (float*)d_out;

    char* Ap = (char*)d_ws;
    char* Wp = (char*)d_ws + (size_t)M_DIM * K_DIM;

    const int n16x = M_DIM * K_DIM / 16;          // 1,048,576
    const int n16w = N_DIM * K_DIM / 16;          // 2,818,048
    const int n16  = n16x + n16w;                 // 3,866,624 -> 15104 blocks
    pack_i8_kernel<<<n16 / 256, 256, 0, stream>>>(
        (const int4*)x, (int4*)Ap, n16x, (const int4*)w, (int4*)Wp, n16);

    dim3 grid(N_DIM / BN, M_DIM / BM);  // (86, 16)
    gemm_i8_kernel<<<grid, 256, 0, stream>>>(Ap, Wp, bias, out);
}